// Round 8
// baseline (352.886 us; speedup 1.0000x reference)
//
#include <hip/hip_runtime.h>

// Problem constants (match reference)
#define N_    100000
#define C_    16
#define F_    16
#define W_    8
#define D_    3
#define NSEG_ 8192
#define BR    16            // n-rows per block in preconv

#define SEGROW (W_*F_)                       // 128 floats
#define SEGBUF ((size_t)NSEG_ * SEGROW)      // floats per dim

typedef __attribute__((ext_vector_type(4))) float f32x4;
typedef __attribute__((ext_vector_type(8))) short bf16x8;

// float -> bf16 round-to-nearest-even
static __device__ __forceinline__ short f2bf(float x) {
    union { float f; unsigned u; } v; v.f = x;
    unsigned r = v.u + 0x7fffu + ((v.u >> 16) & 1u);
    return (short)(r >> 16);
}

// ---------------------------------------------------------------------------
// Sort phase: histogram -> exclusive scan -> scatter (order[] groups points
// by segment id). Replaces 38.4M fp32 atomics with 0.3M int atomics.
// ---------------------------------------------------------------------------
__global__ __launch_bounds__(256) void hist_k(
    const int* __restrict__ index, int* __restrict__ hist)
{
    const int i = blockIdx.y;
    const int n = blockIdx.x * 256 + threadIdx.x;
    if (n < N_) atomicAdd(&hist[i * NSEG_ + index[(size_t)i * N_ + n]], 1);
}

__global__ __launch_bounds__(256) void scan_k(
    const int* __restrict__ hist, int* __restrict__ basep)
{
    const int i = blockIdx.x;
    const int t = threadIdx.x;
    __shared__ int sums[256];

    int run = 0;
#pragma unroll
    for (int j = 0; j < 32; ++j) run += hist[i * NSEG_ + t * 32 + j];
    sums[t] = run;
    __syncthreads();
    for (int off = 1; off < 256; off <<= 1) {
        int v = (t >= off) ? sums[t - off] : 0;
        __syncthreads();
        sums[t] += v;
        __syncthreads();
    }
    int acc = sums[t] - run;        // exclusive prefix of this thread's chunk
#pragma unroll
    for (int j = 0; j < 32; ++j) {
        const int idx = i * NSEG_ + t * 32 + j;
        const int v = hist[idx];
        basep[idx] = acc;
        acc += v;
    }
}

__global__ __launch_bounds__(256) void scatter_k(
    const int* __restrict__ index, const int* __restrict__ basep,
    int* __restrict__ cursor, int* __restrict__ order)
{
    const int i = blockIdx.y;
    const int n = blockIdx.x * 256 + threadIdx.x;
    if (n < N_) {
        const int s = index[(size_t)i * N_ + n];
        const int off = atomicAdd(&cursor[i * NSEG_ + s], 1);
        order[(size_t)i * N_ + basep[i * NSEG_ + s] + off] = n;
    }
}

// ---------------------------------------------------------------------------
// Kernel: gather + 3x3 pre-conv (im2col GEMM on MFMA) + relu -> bf16 convout.
// Same MFMA structure as round 2 but the atomic sink is replaced by an LDS
// repack + coalesced 16B streaming store of the block's 4KB output.
// ---------------------------------------------------------------------------
__global__ __launch_bounds__(256) void preconv_mfma(
    const float* __restrict__ X, const int* __restrict__ inv,
    const float* __restrict__ pre_w, const float* __restrict__ pre_b,
    short* __restrict__ convout)
{
    const int r0 = blockIdx.x * BR;
    const int t  = threadIdx.x;

    __shared__ __align__(16) short xg[20][10][16];   // 6400 B
    __shared__ __align__(16) short wbT[16][160];     // 5120 B
    __shared__ __align__(16) short cbuf[128 * 16];   // 4096 B out repack
    __shared__ float bs[F_];

    // zero the x tile (covers w-pads, halo OOB, and K-pad rows 18/19)
    int* xz = (int*)&xg[0][0][0];
    for (int k = t; k < 20 * 10 * 16 / 2; k += 256) xz[k] = 0;

    // weights: wbT[f][k] = bf16(pre_w[k][f]), zero for k >= 144
    for (int k = t; k < 16 * 160; k += 256) {
        const int f = k / 160, kk = k - f * 160;
        wbT[f][kk] = (kk < 144) ? f2bf(pre_w[kk * 16 + f]) : (short)0;
    }
    if (t < F_) bs[t] = pre_b[t];
    __syncthreads();

    // gather: 144 (row,w) pairs x 2 c-halves; each task = 32B of X -> bf16x8
    for (int k = t; k < 288; k += 256) {
        const int pair = k >> 1, half = k & 1;
        const int row = pair >> 3, w = pair & 7;    // row 0..17
        const int n = r0 - 1 + row;
        if (n >= 0 && n < N_) {
            const int src = inv[(size_t)n * W_ + w];
            const float4 v0 = *(const float4*)&X[(size_t)src * C_ + half * 8];
            const float4 v1 = *(const float4*)&X[(size_t)src * C_ + half * 8 + 4];
            bf16x8 o;
            o[0] = f2bf(v0.x); o[1] = f2bf(v0.y); o[2] = f2bf(v0.z); o[3] = f2bf(v0.w);
            o[4] = f2bf(v1.x); o[5] = f2bf(v1.y); o[6] = f2bf(v1.z); o[7] = f2bf(v1.w);
            *(bf16x8*)&xg[row][w + 1][half * 8] = o;
        }
    }
    __syncthreads();

    const int lane = t & 63;
    const int wv   = t >> 6;
    const int fc   = lane & 15;     // filter col
    const int kb   = lane >> 4;     // k-block 0..3
    const int mA   = lane & 15;     // A-fragment row within tile

#pragma unroll
    for (int tt = 0; tt < 2; ++tt) {
        const int m_base = (wv * 2 + tt) * 16;
        const int m  = m_base + mA;
        const int nl = m >> 3;          // local n (0..15)
        const int w  = m & 7;
        f32x4 acc = {0.f, 0.f, 0.f, 0.f};
#pragma unroll
        for (int s = 0; s < 5; ++s) {
            const int g  = s * 4 + kb;      // 8-wide k-group index
            const int gg = g >> 1;          // (dr,dw) group 0..9
            const int c0 = (g & 1) * 8;
            const int dr = gg / 3;          // 3 -> K-pad (zero rows)
            const int dw = gg - dr * 3;
            const bf16x8 a = *(const bf16x8*)&xg[nl + dr][w + dw][c0];
            const bf16x8 b = *(const bf16x8*)&wbT[fc][s * 32 + kb * 8];
            acc = __builtin_amdgcn_mfma_f32_16x16x32_bf16(a, b, acc, 0, 0, 0);
        }
        // C row = (lane>>4)*4 + r, col = lane&15 -> LDS repack
#pragma unroll
        for (int r = 0; r < 4; ++r) {
            const int mc = m_base + kb * 4 + r;
            cbuf[mc * 16 + fc] = f2bf(fmaxf(acc[r] + bs[fc], 0.f));
        }
    }
    __syncthreads();
    // coalesced stream-out: 256 threads x 16B = 4KB block output
    *(bf16x8*)&convout[(size_t)r0 * SEGROW + t * 8] = *(bf16x8*)&cbuf[t * 8];
}

// ---------------------------------------------------------------------------
// Kernel: per-segment sum (no atomics). One wave per segment; lane l owns
// elements 2l, 2l+1 of the 128-float row; fp32 accumulation.
// ---------------------------------------------------------------------------
__global__ __launch_bounds__(256) void segsum_k(
    const short* __restrict__ convout, const int* __restrict__ order,
    const int* __restrict__ hist, const int* __restrict__ basep,
    float* __restrict__ seg)
{
    const int t = threadIdx.x;
    const int s = blockIdx.x * 4 + (t >> 6);    // segment id
    const int l = t & 63;

    const int cnt  = hist[s];
    const int base = basep[s];
    const unsigned* cp = (const unsigned*)convout;

    float a0 = 0.f, a1 = 0.f;
    for (int p = 0; p < cnt; ++p) {
        const int n = order[base + p];
        const unsigned v = cp[(size_t)n * 64 + l];
        union { unsigned u; float f; } lo, hi;
        lo.u = v << 16;
        hi.u = v & 0xffff0000u;
        a0 += lo.f;
        a1 += hi.f;
    }
    *(float2*)&seg[(size_t)s * SEGROW + 2 * l] = make_float2(a0, a1);
}

// ---------------------------------------------------------------------------
// Kernel: (3,1) post-conv + relu over seg -> post.  One thread per output.
// ---------------------------------------------------------------------------
__global__ __launch_bounds__(256) void postconv(
    const float* __restrict__ seg, const float* __restrict__ post_w,
    const float* __restrict__ post_b, float* __restrict__ post)
{
    const int i = blockIdx.y;
    const int t = threadIdx.x;

    __shared__ float ws[3][F_][F_];     // [kh][fi][fo]
    __shared__ float bs[F_];
    for (int k = t; k < 3 * F_ * F_; k += 256)
        (&ws[0][0][0])[k] = post_w[i * 3 * F_ * F_ + k];
    if (t < F_) bs[t] = post_b[i * F_ + t];
    __syncthreads();

    const int idx = blockIdx.x * 256 + t;   // over NSEG_*W_*F_ = 1,048,576
    const int fo  = idx & 15;
    const int w   = (idx >> 4) & 7;
    const int s   = idx >> 7;

    float acc = bs[fo];
#pragma unroll
    for (int dh = 0; dh < 3; ++dh) {
        const int ss = s + dh - 1;
        if (ss < 0 || ss >= NSEG_) continue;
        const float* sp = seg + ((size_t)i * NSEG_ + ss) * SEGROW + w * F_;
        const float4 s0 = *(const float4*)(sp);
        const float4 s1 = *(const float4*)(sp + 4);
        const float4 s2 = *(const float4*)(sp + 8);
        const float4 s3 = *(const float4*)(sp + 12);
        const float sv[16] = {s0.x, s0.y, s0.z, s0.w, s1.x, s1.y, s1.z, s1.w,
                              s2.x, s2.y, s2.z, s2.w, s3.x, s3.y, s3.z, s3.w};
#pragma unroll
        for (int fi = 0; fi < F_; ++fi)
            acc += sv[fi] * ws[dh][fi][fo];
    }
    post[(size_t)i * SEGBUF + idx] = fmaxf(acc, 0.f);
}

// ---------------------------------------------------------------------------
// Kernel: Y[n] = sum_i post[i][index[i][n]]   (float4-vectorized)
// ---------------------------------------------------------------------------
__global__ __launch_bounds__(256) void gather_sum(
    const float* __restrict__ post, const int* __restrict__ index,
    float* __restrict__ Y)
{
    const int gt = blockIdx.x * 256 + threadIdx.x;  // over N_*32 float4
    if (gt >= N_ * 32) return;
    const int q = gt & 31;
    const int n = gt >> 5;

    float4 acc = make_float4(0.f, 0.f, 0.f, 0.f);
#pragma unroll
    for (int i = 0; i < D_; ++i) {
        const int s = index[(size_t)i * N_ + n];
        const float4 v = *(const float4*)&post[(size_t)i * SEGBUF +
                                               (size_t)s * SEGROW + q * 4];
        acc.x += v.x; acc.y += v.y; acc.z += v.z; acc.w += v.w;
    }
    *(float4*)&Y[(size_t)n * SEGROW + q * 4] = acc;
}

// ---------------------------------------------------------------------------
extern "C" void kernel_launch(void* const* d_in, const int* in_sizes, int n_in,
                              void* d_out, int out_size, void* d_ws, size_t ws_size,
                              hipStream_t stream)
{
    const float* X      = (const float*)d_in[0];
    const int*   inv    = (const int*)  d_in[1];
    const int*   index  = (const int*)  d_in[2];
    const float* pre_w  = (const float*)d_in[3];
    const float* pre_b  = (const float*)d_in[4];
    const float* post_w = (const float*)d_in[5];
    const float* post_b = (const float*)d_in[6];
    float*       Y      = (float*)d_out;

    // workspace layout (bytes, all 256B-aligned):
    //   seg     [3][8192][128] f32   = 12.58 MB
    //   post    [3][8192][128] f32   = 12.58 MB
    //   convout [100000][128] bf16   = 25.6  MB (reused across dims)
    //   order   [3][100000] i32      = 1.2   MB
    //   hist    [3][8192] i32, cursor [3][8192] i32 (contiguous -> 1 memset)
    //   basep   [3][8192] i32
    char* p = (char*)d_ws;
    float* seg     = (float*)p;               p += D_ * SEGBUF * sizeof(float);
    float* post    = (float*)p;               p += D_ * SEGBUF * sizeof(float);
    short* convout = (short*)p;               p += (size_t)N_ * SEGROW * sizeof(short);
    int*   order   = (int*)p;                 p += (size_t)D_ * N_ * sizeof(int);
    int*   hist    = (int*)p;                 p += D_ * NSEG_ * sizeof(int);
    int*   cursor  = (int*)p;                 p += D_ * NSEG_ * sizeof(int);
    int*   basep   = (int*)p;                 p += D_ * NSEG_ * sizeof(int);

    hipMemsetAsync(hist, 0, 2 * D_ * NSEG_ * sizeof(int), stream);  // hist+cursor

    const int nb = (N_ + 255) / 256;
    hist_k   <<<dim3(nb, D_), 256, 0, stream>>>(index, hist);
    scan_k   <<<D_, 256, 0, stream>>>(hist, basep);
    scatter_k<<<dim3(nb, D_), 256, 0, stream>>>(index, basep, cursor, order);

    for (int i = 0; i < D_; ++i) {
        preconv_mfma<<<N_ / BR, 256, 0, stream>>>(
            X, inv + (size_t)i * N_ * W_, pre_w + i * 2304, pre_b + i * F_,
            convout);
        segsum_k<<<NSEG_ / 4, 256, 0, stream>>>(
            convout, order + (size_t)i * N_, hist + i * NSEG_,
            basep + i * NSEG_, seg + (size_t)i * SEGBUF);
    }

    postconv<<<dim3((NSEG_ * W_ * F_) / 256, D_), 256, 0, stream>>>(
        seg, post_w, post_b, post);
    gather_sum<<<dim3((N_ * 32 + 255) / 256), 256, 0, stream>>>(post, index, Y);
}

// Round 11
// 263.758 us; speedup vs baseline: 1.3379x; 1.3379x over previous
//
#include <hip/hip_runtime.h>

// Problem constants (match reference)
#define N_    100000
#define C_    16
#define F_    16
#define W_    8
#define D_    3
#define NSEG_ 8192
#define BR    16            // n-rows per block in preconv

#define SEGROW (W_*F_)                       // 128 floats
#define SEGBUF ((size_t)NSEG_ * SEGROW)      // floats per dim

typedef __attribute__((ext_vector_type(4)))  float f32x4;
typedef __attribute__((ext_vector_type(8)))  short bf16x8;
typedef __attribute__((ext_vector_type(16))) short bf16x16;   // 32B

// float -> bf16 round-to-nearest-even
static __device__ __forceinline__ short f2bf(float x) {
    union { float f; unsigned u; } v; v.f = x;
    unsigned r = v.u + 0x7fffu + ((v.u >> 16) & 1u);
    return (short)(r >> 16);
}

// ---------------------------------------------------------------------------
// Prep 1: X (100000 x 16 f32) -> Xbf (bf16). 8 elements/thread.
// ---------------------------------------------------------------------------
__global__ __launch_bounds__(256) void xprep_k(
    const float* __restrict__ X, short* __restrict__ Xbf)
{
    const int gid = blockIdx.x * 256 + threadIdx.x;     // over 200000
    if (gid >= (N_ * C_) / 8) return;
    const float4 v0 = *(const float4*)&X[(size_t)gid * 8];
    const float4 v1 = *(const float4*)&X[(size_t)gid * 8 + 4];
    bf16x8 o;
    o[0] = f2bf(v0.x); o[1] = f2bf(v0.y); o[2] = f2bf(v0.z); o[3] = f2bf(v0.w);
    o[4] = f2bf(v1.x); o[5] = f2bf(v1.y); o[6] = f2bf(v1.z); o[7] = f2bf(v1.w);
    *(bf16x8*)&Xbf[(size_t)gid * 8] = o;
}

// ---------------------------------------------------------------------------
// Prep 2: pre_w -> wbT_g[i][f][kk] bf16 (B^T, K padded 144->160 with zeros).
// 3*16*160 = 7680 entries, grid 30 x 256.
// ---------------------------------------------------------------------------
__global__ __launch_bounds__(256) void wprep_k(
    const float* __restrict__ pre_w, short* __restrict__ wbT_g)
{
    const int k = blockIdx.x * 256 + threadIdx.x;       // over 7680
    const int i  = k / 2560;
    const int r  = k - i * 2560;
    const int f  = r / 160;
    const int kk = r - f * 160;
    wbT_g[k] = (kk < 144) ? f2bf(pre_w[i * 2304 + kk * 16 + f]) : (short)0;
}

// ---------------------------------------------------------------------------
// Main: gather + 3x3 pre-conv (im2col GEMM on MFMA) + relu + atomic segment
// accumulate. Round-2 structure (fused atomics, one launch for all dims),
// inputs pre-staged bf16: gather = one 32B load per (row,w) task, weight
// staging = pure LDS copy. No f2bf in the hot path.
// Fixes vs round 9: (a) gather loads the FULL 32B row (bf16x16, was bf16x8
// = channels 0-7 only); (b) __syncthreads() between xg-zeroing and gather
// (round 9 raced zero-writes against gather-writes).
// ---------------------------------------------------------------------------
__global__ __launch_bounds__(256) void preconv_seg_mfma(
    const short* __restrict__ Xbf, const int* __restrict__ inv,
    const int* __restrict__ index, const short* __restrict__ wbT_g,
    const float* __restrict__ pre_b, float* __restrict__ seg)
{
    const int i  = blockIdx.y;          // dim 0..2
    const int r0 = blockIdx.x * BR;
    const int t  = threadIdx.x;

    __shared__ __align__(32) short xg[20][10][16];   // 6400 B
    __shared__ __align__(16) short wbT[16][160];     // 5120 B
    __shared__ float bs[F_];
    __shared__ int   sidx[BR];

    // zero the x tile (covers w-pads, halo OOB, and K-pad rows 18/19)
    int* xz = (int*)&xg[0][0][0];
    for (int k = t; k < 20 * 10 * 16 / 2; k += 256) xz[k] = 0;

    // stage weights (pure bf16 copy, 320 x 16B)
    {
        const bf16x8* src = (const bf16x8*)(wbT_g + i * 2560);
        bf16x8* dst = (bf16x8*)&wbT[0][0];
        dst[t] = src[t];                       // 256 chunks
        if (t < 64) dst[256 + t] = src[256 + t];
    }
    if (t < F_) bs[t] = pre_b[i * F_ + t];
    if (t < BR) sidx[t] = index[(size_t)i * N_ + r0 + t];
    __syncthreads();                           // zero-writes before gather-writes

    // gather: 18 rows x 8 w = 144 tasks, each one full 32B bf16 row of X
    if (t < 144) {
        const int row = t >> 3, w = t & 7;     // row 0..17
        const int n = r0 - 1 + row;
        if (n >= 0 && n < N_) {
            const int src = inv[((size_t)i * N_ + n) * W_ + w];
            *(bf16x16*)&xg[row][w + 1][0] =
                *(const bf16x16*)&Xbf[(size_t)src * C_];
        }
    }
    __syncthreads();

    const int lane = t & 63;
    const int wv   = t >> 6;
    const int fc   = lane & 15;     // filter col
    const int kb   = lane >> 4;     // k-block 0..3
    const int mA   = lane & 15;     // A-fragment row within tile

#pragma unroll
    for (int tt = 0; tt < 2; ++tt) {
        const int m_base = (wv * 2 + tt) * 16;
        const int m  = m_base + mA;
        const int nl = m >> 3;          // local n (0..15)
        const int w  = m & 7;
        f32x4 acc = {0.f, 0.f, 0.f, 0.f};
#pragma unroll
        for (int s = 0; s < 5; ++s) {
            const int g  = s * 4 + kb;      // 8-wide k-group index
            const int gg = g >> 1;          // (dr,dw) group 0..9
            const int c0 = (g & 1) * 8;
            const int dr = gg / 3;          // 3 -> K-pad (zero rows)
            const int dw = gg - dr * 3;
            const bf16x8 a = *(const bf16x8*)&xg[nl + dr][w + dw][c0];
            const bf16x8 b = *(const bf16x8*)&wbT[fc][s * 32 + kb * 8];
            acc = __builtin_amdgcn_mfma_f32_16x16x32_bf16(a, b, acc, 0, 0, 0);
        }
        // epilogue: C row = (lane>>4)*4 + r, col = lane&15 -> atomic segsum
#pragma unroll
        for (int r = 0; r < 4; ++r) {
            const int mc  = m_base + kb * 4 + r;
            const int nlc = mc >> 3, wc = mc & 7;
            const float v = fmaxf(acc[r] + bs[fc], 0.f);
            atomicAdd(&seg[((size_t)i * NSEG_ + sidx[nlc]) * SEGROW + wc * F_ + fc], v);
        }
    }
}

// ---------------------------------------------------------------------------
// Kernel: (3,1) post-conv + relu over seg -> post.  One thread per output.
// ---------------------------------------------------------------------------
__global__ __launch_bounds__(256) void postconv(
    const float* __restrict__ seg, const float* __restrict__ post_w,
    const float* __restrict__ post_b, float* __restrict__ post)
{
    const int i = blockIdx.y;
    const int t = threadIdx.x;

    __shared__ float ws[3][F_][F_];     // [kh][fi][fo]
    __shared__ float bs[F_];
    for (int k = t; k < 3 * F_ * F_; k += 256)
        (&ws[0][0][0])[k] = post_w[i * 3 * F_ * F_ + k];
    if (t < F_) bs[t] = post_b[i * F_ + t];
    __syncthreads();

    const int idx = blockIdx.x * 256 + t;   // over NSEG_*W_*F_ = 1,048,576
    const int fo  = idx & 15;
    const int w   = (idx >> 4) & 7;
    const int s   = idx >> 7;

    float acc = bs[fo];
#pragma unroll
    for (int dh = 0; dh < 3; ++dh) {
        const int ss = s + dh - 1;
        if (ss < 0 || ss >= NSEG_) continue;
        const float* sp = seg + ((size_t)i * NSEG_ + ss) * SEGROW + w * F_;
        const float4 s0 = *(const float4*)(sp);
        const float4 s1 = *(const float4*)(sp + 4);
        const float4 s2 = *(const float4*)(sp + 8);
        const float4 s3 = *(const float4*)(sp + 12);
        const float sv[16] = {s0.x, s0.y, s0.z, s0.w, s1.x, s1.y, s1.z, s1.w,
                              s2.x, s2.y, s2.z, s2.w, s3.x, s3.y, s3.z, s3.w};
#pragma unroll
        for (int fi = 0; fi < F_; ++fi)
            acc += sv[fi] * ws[dh][fi][fo];
    }
    post[(size_t)i * SEGBUF + idx] = fmaxf(acc, 0.f);
}

// ---------------------------------------------------------------------------
// Kernel: Y[n] = sum_i post[i][index[i][n]]   (float4-vectorized)
// ---------------------------------------------------------------------------
__global__ __launch_bounds__(256) void gather_sum(
    const float* __restrict__ post, const int* __restrict__ index,
    float* __restrict__ Y)
{
    const int gt = blockIdx.x * 256 + threadIdx.x;  // over N_*32 float4
    if (gt >= N_ * 32) return;
    const int q = gt & 31;
    const int n = gt >> 5;

    float4 acc = make_float4(0.f, 0.f, 0.f, 0.f);
#pragma unroll
    for (int i = 0; i < D_; ++i) {
        const int s = index[(size_t)i * N_ + n];
        const float4 v = *(const float4*)&post[(size_t)i * SEGBUF +
                                               (size_t)s * SEGROW + q * 4];
        acc.x += v.x; acc.y += v.y; acc.z += v.z; acc.w += v.w;
    }
    *(float4*)&Y[(size_t)n * SEGROW + q * 4] = acc;
}

// ---------------------------------------------------------------------------
extern "C" void kernel_launch(void* const* d_in, const int* in_sizes, int n_in,
                              void* d_out, int out_size, void* d_ws, size_t ws_size,
                              hipStream_t stream)
{
    const float* X      = (const float*)d_in[0];
    const int*   inv    = (const int*)  d_in[1];
    const int*   index  = (const int*)  d_in[2];
    const float* pre_w  = (const float*)d_in[3];
    const float* pre_b  = (const float*)d_in[4];
    const float* post_w = (const float*)d_in[5];
    const float* post_b = (const float*)d_in[6];
    float*       Y      = (float*)d_out;

    // workspace: seg[3][8192][128] f32 (12.6MB) | post same (12.6MB)
    //          | Xbf[100000][16] bf16 (3.2MB)   | wbT_g[3][16][160] bf16 (15KB)
    char* p = (char*)d_ws;
    float* seg   = (float*)p;   p += D_ * SEGBUF * sizeof(float);
    float* post  = (float*)p;   p += D_ * SEGBUF * sizeof(float);
    short* Xbf   = (short*)p;   p += (size_t)N_ * C_ * sizeof(short);
    short* wbT_g = (short*)p;   p += D_ * F_ * 160 * sizeof(short);

    hipMemsetAsync(seg, 0, D_ * SEGBUF * sizeof(float), stream);

    xprep_k<<<(N_ * C_ / 8 + 255) / 256, 256, 0, stream>>>(X, Xbf);
    wprep_k<<<30, 256, 0, stream>>>(pre_w, wbT_g);

    preconv_seg_mfma<<<dim3(N_ / BR, D_), 256, 0, stream>>>(
        Xbf, inv, index, wbT_g, pre_b, seg);

    postconv<<<dim3((NSEG_ * W_ * F_) / 256, D_), 256, 0, stream>>>(
        seg, post_w, post_b, post);
    gather_sum<<<dim3((N_ * 32 + 255) / 256), 256, 0, stream>>>(post, index, Y);
}